// Round 4
// baseline (1157.792 us; speedup 1.0000x reference)
//
#include <hip/hip_runtime.h>

#define Hdim 128
#define Idim 32
#define Bdim 4096
#define Sdim 512
#define ROWS 8       // 8 batch rows/block -> 512 blocks -> 2 blocks/CU co-resident
#define THREADS 512
#define HPAD 138     // 138 halves = 276B row stride (69 dwords, odd -> staggered banks)
#define XPAD 40      // 32 + 8 halves pad -> 80B row stride

typedef _Float16 half8 __attribute__((ext_vector_type(8)));
typedef _Float16 half4v __attribute__((ext_vector_type(4)));
typedef float f32x4 __attribute__((ext_vector_type(4)));

#define MFMA16(a, b, c) __builtin_amdgcn_mfma_f32_16x16x32_f16((a), (b), (c), 0, 0, 0)

__device__ __forceinline__ float sigm(float x) {
    return __builtin_amdgcn_rcpf(1.0f + __builtin_amdgcn_exp2f(-1.44269504f * x));
}
__device__ __forceinline__ float tanh_fast(float x) {
    return 1.0f - 2.0f * __builtin_amdgcn_rcpf(1.0f + __builtin_amdgcn_exp2f(2.88539008f * x));
}

__device__ __forceinline__ half8 load8(const float* __restrict__ p) {
    float4 a = *(const float4*)p;
    float4 b = *(const float4*)(p + 4);
    half8 r;
    r[0] = (_Float16)a.x; r[1] = (_Float16)a.y; r[2] = (_Float16)a.z; r[3] = (_Float16)a.w;
    r[4] = (_Float16)b.x; r[5] = (_Float16)b.y; r[6] = (_Float16)b.z; r[7] = (_Float16)b.w;
    return r;
}

extern "C" __global__ __launch_bounds__(THREADS, 4)
void rnn_ae(const float* __restrict__ x, const float* __restrict__ h0,
            const float* __restrict__ eWih, const float* __restrict__ eWhh,
            const float* __restrict__ eBih, const float* __restrict__ eBhh,
            const float* __restrict__ dWih, const float* __restrict__ dWhh,
            const float* __restrict__ dBih, const float* __restrict__ dBhh,
            const float* __restrict__ linW, const float* __restrict__ linB,
            float* __restrict__ out)
{
    __shared__ _Float16 hlds[2][ROWS][HPAD];
    __shared__ _Float16 xlds[2][ROWS][XPAD];

    const int tid = threadIdx.x;
    const int w   = tid >> 6;            // wave 0..7 -> hidden-col slice [16w,16w+16)
    const int l   = tid & 63;
    const int cc  = l & 15;              // A-row / B-col / C-col lane field
    const int q   = l >> 4;              // quad 0..3
    const int kb  = q * 8;               // A/B k-base
    const int r0  = (q >> 1) * 2;        // acc index base (dup-C trick: 2 elems/lane)
    const int rl0 = (q & 1) * 4 + (q >> 1) * 2;  // this lane's first owned batch row (0..7)
    const int ar7 = cc & 7;              // A-read row (rows 8-15 duplicate 0-7)
    const int row0 = blockIdx.x * ROWS;
    const int j   = w * 16 + cc;         // this lane's hidden/gate column

    const f32x4 zero = {0.f, 0.f, 0.f, 0.f};

    auto stage = [&](int t, int buf) {   // tid<64 only: stage x[:,t,:] -> xlds[buf] as f16
        int row = tid >> 3;              // 0..7
        int c4  = (tid & 7) << 2;        // 0,4,..,28
        float4 v = *(const float4*)(x + ((size_t)(row0 + row) * Sdim + (size_t)t) * Idim + c4);
        half4v hv;
        hv[0] = (_Float16)v.x; hv[1] = (_Float16)v.y; hv[2] = (_Float16)v.z; hv[3] = (_Float16)v.w;
        *(half4v*)&xlds[buf][row][c4] = hv;
    };

    // ---------------- encoder weights -> registers (held for 512 steps) ----------------
    half8 bwi[3], bwh[3][4];
    float br, bz, bni, bnh;
    #pragma unroll
    for (int g = 0; g < 3; ++g) {
        int n = g * Hdim + j;                      // gate row in [3H] (r,z,n order)
        bwi[g] = load8(eWih + n * Idim + kb);      // B[k][n] = W[n][k]
        #pragma unroll
        for (int kk = 0; kk < 4; ++kk)
            bwh[g][kk] = load8(eWhh + n * Hdim + kk * 32 + kb);
    }
    br  = eBih[j] + eBhh[j];
    bz  = eBih[Hdim + j] + eBhh[Hdim + j];
    bni = eBih[2 * Hdim + j];
    bnh = eBhh[2 * Hdim + j];

    float hreg[2];
    #pragma unroll
    for (int r = 0; r < 2; ++r) {
        hreg[r] = h0[(size_t)(row0 + rl0 + r) * Hdim + j];
        hlds[0][rl0 + r][j] = (_Float16)hreg[r];
    }
    if (tid < 64) stage(0, 0);
    __syncthreads();

    // ---------------- encoder scan ----------------
    int cur = 0;
    for (int t = 0; t < Sdim; ++t) {
        half8 ax  = *(const half8*)&xlds[cur][ar7][kb];
        half8 ah0 = *(const half8*)&hlds[cur][ar7][kb];
        half8 ah1 = *(const half8*)&hlds[cur][ar7][32 + kb];
        half8 ah2 = *(const half8*)&hlds[cur][ar7][64 + kb];
        half8 ah3 = *(const half8*)&hlds[cur][ar7][96 + kb];
        if (tid < 64 && t + 1 < Sdim) stage(t + 1, cur ^ 1);

        f32x4 ar  = MFMA16(ax, bwi[0], zero);
        f32x4 az  = MFMA16(ax, bwi[1], zero);
        f32x4 ani = MFMA16(ax, bwi[2], zero);
        f32x4 anh = zero;
        ar  = MFMA16(ah0, bwh[0][0], ar);
        ar  = MFMA16(ah1, bwh[0][1], ar);
        ar  = MFMA16(ah2, bwh[0][2], ar);
        ar  = MFMA16(ah3, bwh[0][3], ar);
        az  = MFMA16(ah0, bwh[1][0], az);
        az  = MFMA16(ah1, bwh[1][1], az);
        az  = MFMA16(ah2, bwh[1][2], az);
        az  = MFMA16(ah3, bwh[1][3], az);
        anh = MFMA16(ah0, bwh[2][0], anh);
        anh = MFMA16(ah1, bwh[2][1], anh);
        anh = MFMA16(ah2, bwh[2][2], anh);
        anh = MFMA16(ah3, bwh[2][3], anh);

        #pragma unroll
        for (int r = 0; r < 2; ++r) {
            int   ai = r0 + r;                    // acc slot (dup rows: valid data)
            float R  = sigm(ar[ai] + br);
            float Z  = sigm(az[ai] + bz);
            float Nn = tanh_fast(ani[ai] + bni + R * (anh[ai] + bnh)); // r gates only h-part
            float hn = Nn + Z * (hreg[r] - Nn);                        // (1-z)n + z h
            hreg[r] = hn;
            hlds[cur ^ 1][rl0 + r][j] = (_Float16)hn;
        }
        __syncthreads();
        cur ^= 1;
    }

    // encoder final hidden -> output tail
    {
        const size_t HOFF = (size_t)Bdim * Sdim * Idim;
        #pragma unroll
        for (int r = 0; r < 2; ++r)
            out[HOFF + (size_t)(row0 + rl0 + r) * Hdim + j] = hreg[r];
    }

    // ---------------- decoder weights -> registers ----------------
    #pragma unroll
    for (int g = 0; g < 3; ++g) {
        int n = g * Hdim + j;
        bwi[g] = load8(dWih + n * Idim + kb);
        #pragma unroll
        for (int kk = 0; kk < 4; ++kk)
            bwh[g][kk] = load8(dWhh + n * Hdim + kk * 32 + kb);
    }
    br  = dBih[j] + dBhh[j];
    bz  = dBih[Hdim + j] + dBhh[Hdim + j];
    bni = dBih[2 * Hdim + j];
    bnh = dBhh[2 * Hdim + j];

    half8 blin[4];
    float lb = 0.f;
    {
        half8 hz;
        #pragma unroll
        for (int e = 0; e < 8; ++e) hz[e] = (_Float16)0.f;
        blin[0] = hz; blin[1] = hz; blin[2] = hz; blin[3] = hz;
    }
    const int ycol = w * 16 + cc;        // valid (in-range) only for w<2
    if (w < 2) {
        #pragma unroll
        for (int kk = 0; kk < 4; ++kk)
            blin[kk] = load8(linW + ycol * Hdim + kk * 32 + kb);
        lb = linB[ycol];
    }
    if (tid < 64) stage(0, 0);           // decoder seed: x[:,0,:]  (h_enc already in hlds[0])
    __syncthreads();

    // ---------------- decoder scan (autoregressive) ----------------
    cur = 0;
    for (int t = 0; t < Sdim; ++t) {
        half8 ax  = *(const half8*)&xlds[cur][ar7][kb];
        half8 ah0 = *(const half8*)&hlds[cur][ar7][kb];
        half8 ah1 = *(const half8*)&hlds[cur][ar7][32 + kb];
        half8 ah2 = *(const half8*)&hlds[cur][ar7][64 + kb];
        half8 ah3 = *(const half8*)&hlds[cur][ar7][96 + kb];

        f32x4 ar  = MFMA16(ax, bwi[0], zero);
        f32x4 az  = MFMA16(ax, bwi[1], zero);
        f32x4 ani = MFMA16(ax, bwi[2], zero);
        f32x4 anh = zero;
        ar  = MFMA16(ah0, bwh[0][0], ar);
        ar  = MFMA16(ah1, bwh[0][1], ar);
        ar  = MFMA16(ah2, bwh[0][2], ar);
        ar  = MFMA16(ah3, bwh[0][3], ar);
        az  = MFMA16(ah0, bwh[1][0], az);
        az  = MFMA16(ah1, bwh[1][1], az);
        az  = MFMA16(ah2, bwh[1][2], az);
        az  = MFMA16(ah3, bwh[1][3], az);
        anh = MFMA16(ah0, bwh[2][0], anh);
        anh = MFMA16(ah1, bwh[2][1], anh);
        anh = MFMA16(ah2, bwh[2][2], anh);
        anh = MFMA16(ah3, bwh[2][3], anh);

        #pragma unroll
        for (int r = 0; r < 2; ++r) {
            int   ai = r0 + r;
            float R  = sigm(ar[ai] + br);
            float Z  = sigm(az[ai] + bz);
            float Nn = tanh_fast(ani[ai] + bni + R * (anh[ai] + bnh));
            float hn = Nn + Z * (hreg[r] - Nn);
            hreg[r] = hn;
            hlds[cur ^ 1][rl0 + r][j] = (_Float16)hn;
        }
        __syncthreads();   // h_{t+1} f16 visible for y-GEMM

        if (w < 2) {       // y = h_new @ linW^T + lb ; feed back as next x
            half8 p0 = *(const half8*)&hlds[cur ^ 1][ar7][kb];
            half8 p1 = *(const half8*)&hlds[cur ^ 1][ar7][32 + kb];
            half8 p2 = *(const half8*)&hlds[cur ^ 1][ar7][64 + kb];
            half8 p3 = *(const half8*)&hlds[cur ^ 1][ar7][96 + kb];
            f32x4 ay = MFMA16(p0, blin[0], zero);
            ay = MFMA16(p1, blin[1], ay);
            ay = MFMA16(p2, blin[2], ay);
            ay = MFMA16(p3, blin[3], ay);
            #pragma unroll
            for (int r = 0; r < 2; ++r) {
                float yv = ay[r0 + r] + lb;
                out[((size_t)(row0 + rl0 + r) * Sdim + (size_t)t) * Idim + ycol] = yv;
                xlds[cur ^ 1][rl0 + r][ycol] = (_Float16)yv;
            }
        }
        __syncthreads();   // next step's x ready
        cur ^= 1;
    }
}

extern "C" void kernel_launch(void* const* d_in, const int* in_sizes, int n_in,
                              void* d_out, int out_size, void* d_ws, size_t ws_size,
                              hipStream_t stream) {
    (void)in_sizes; (void)n_in; (void)d_ws; (void)ws_size; (void)out_size;
    const float* x    = (const float*)d_in[0];
    const float* h0   = (const float*)d_in[1];
    const float* eWih = (const float*)d_in[2];
    const float* eWhh = (const float*)d_in[3];
    const float* eBih = (const float*)d_in[4];
    const float* eBhh = (const float*)d_in[5];
    const float* dWih = (const float*)d_in[6];
    const float* dWhh = (const float*)d_in[7];
    const float* dBih = (const float*)d_in[8];
    const float* dBhh = (const float*)d_in[9];
    const float* linW = (const float*)d_in[10];
    const float* linB = (const float*)d_in[11];
    rnn_ae<<<dim3(Bdim / ROWS), dim3(THREADS), 0, stream>>>(
        x, h0, eWih, eWhh, eBih, eBhh, dWih, dWhh, dBih, dBhh, linW, linB,
        (float*)d_out);
}

// Round 5
// 847.905 us; speedup vs baseline: 1.3655x; 1.3655x over previous
//
#include <hip/hip_runtime.h>

#define Hdim 128
#define Idim 32
#define Bdim 4096
#define Sdim 512
#define ROWS 16
#define THREADS 512
#define HPAD 136   // 272B row stride: 16B-aligned (b128 ok), rows stagger 4 banks -> 2-way max on A-reads
#define XPAD 40    // 80B row stride, 16B aligned

typedef _Float16 half8 __attribute__((ext_vector_type(8)));
typedef _Float16 half4v __attribute__((ext_vector_type(4)));
typedef float f32x4 __attribute__((ext_vector_type(4)));

#define MFMA16(a, b, c) __builtin_amdgcn_mfma_f32_16x16x32_f16((a), (b), (c), 0, 0, 0)

// LDS-only barrier: no vmcnt drain (global loads are covered by register deps,
// y-stores are never read). This keeps HBM latency off the per-step critical path.
#define BARRIER() asm volatile("s_waitcnt lgkmcnt(0)\n\ts_barrier" ::: "memory")

__device__ __forceinline__ float sigm(float x) {
    return __builtin_amdgcn_rcpf(1.0f + __builtin_amdgcn_exp2f(-1.44269504f * x));
}
__device__ __forceinline__ float tanh_fast(float x) {
    return 1.0f - 2.0f * __builtin_amdgcn_rcpf(1.0f + __builtin_amdgcn_exp2f(2.88539008f * x));
}

__device__ __forceinline__ half8 load8(const float* __restrict__ p) {
    float4 a = *(const float4*)p;
    float4 b = *(const float4*)(p + 4);
    half8 r;
    r[0] = (_Float16)a.x; r[1] = (_Float16)a.y; r[2] = (_Float16)a.z; r[3] = (_Float16)a.w;
    r[4] = (_Float16)b.x; r[5] = (_Float16)b.y; r[6] = (_Float16)b.z; r[7] = (_Float16)b.w;
    return r;
}

extern "C" __global__ __launch_bounds__(THREADS, 2)
void rnn_ae(const float* __restrict__ x, const float* __restrict__ h0,
            const float* __restrict__ eWih, const float* __restrict__ eWhh,
            const float* __restrict__ eBih, const float* __restrict__ eBhh,
            const float* __restrict__ dWih, const float* __restrict__ dWhh,
            const float* __restrict__ dBih, const float* __restrict__ dBhh,
            const float* __restrict__ linW, const float* __restrict__ linB,
            float* __restrict__ out)
{
    __shared__ _Float16 hlds[2][ROWS][HPAD];
    __shared__ _Float16 xlds[2][ROWS][XPAD];

    const int tid = threadIdx.x;
    const int w   = tid >> 6;          // wave 0..7 -> hidden-col slice [16w,16w+16)
    const int l   = tid & 63;
    const int cc  = l & 15;            // A-row / B-col / C-col lane field
    const int cq  = l >> 4;            // quad 0..3
    const int kb  = cq * 8;            // A/B k-base
    const int rb  = cq * 4;            // C row-base (batch rows)
    const int row0 = blockIdx.x * ROWS;
    const int j   = w * 16 + cc;       // this lane's hidden/gate column
    const int srow = tid >> 3;         // staging row (tid<128)
    const int sc4  = (tid & 7) << 2;   // staging col

    const f32x4 zero = {0.f, 0.f, 0.f, 0.f};

    // ---------------- encoder weights -> registers (held for 512 steps) ----------------
    half8 bwi[3], bwh[3][4];
    float br, bz, bni, bnh;
    #pragma unroll
    for (int g = 0; g < 3; ++g) {
        int n = g * Hdim + j;                      // gate row in [3H] (r,z,n order)
        bwi[g] = load8(eWih + n * Idim + kb);      // B[k][n] = W[n][k]
        #pragma unroll
        for (int kk = 0; kk < 4; ++kk)
            bwh[g][kk] = load8(eWhh + n * Hdim + kk * 32 + kb);
    }
    br  = eBih[j] + eBhh[j];
    bz  = eBih[Hdim + j] + eBhh[Hdim + j];
    bni = eBih[2 * Hdim + j];
    bnh = eBhh[2 * Hdim + j];

    float hreg[4];
    #pragma unroll
    for (int r = 0; r < 4; ++r) {
        hreg[r] = h0[(size_t)(row0 + rb + r) * Hdim + j];
        hlds[0][rb + r][j] = (_Float16)hreg[r];
    }

    // x pipeline prologue: x[0] -> xlds[0]; x[1] -> regs (xv)
    float4 xv = {0.f, 0.f, 0.f, 0.f};
    if (tid < 128) {
        float4 v = *(const float4*)(x + ((size_t)(row0 + srow) * Sdim + 0) * Idim + sc4);
        half4v hv;
        hv[0] = (_Float16)v.x; hv[1] = (_Float16)v.y; hv[2] = (_Float16)v.z; hv[3] = (_Float16)v.w;
        *(half4v*)&xlds[0][srow][sc4] = hv;
        xv = *(const float4*)(x + ((size_t)(row0 + srow) * Sdim + 1) * Idim + sc4);
    }
    __syncthreads();

    // ---------------- encoder scan ----------------
    int cur = 0;
    for (int t = 0; t < Sdim; ++t) {
        half8 ax  = *(const half8*)&xlds[cur][cc][kb];
        half8 ah0 = *(const half8*)&hlds[cur][cc][kb];
        half8 ah1 = *(const half8*)&hlds[cur][cc][32 + kb];
        half8 ah2 = *(const half8*)&hlds[cur][cc][64 + kb];
        half8 ah3 = *(const half8*)&hlds[cur][cc][96 + kb];

        if (tid < 128) {
            if (t + 1 < Sdim) {            // write x[t+1] (in regs since step t-1) to LDS
                half4v hv;
                hv[0] = (_Float16)xv.x; hv[1] = (_Float16)xv.y;
                hv[2] = (_Float16)xv.z; hv[3] = (_Float16)xv.w;
                *(half4v*)&xlds[cur ^ 1][srow][sc4] = hv;
            }
            if (t + 2 < Sdim)              // issue load of x[t+2]; lands during step t+1
                xv = *(const float4*)(x + ((size_t)(row0 + srow) * Sdim + (size_t)(t + 2)) * Idim + sc4);
        }

        f32x4 ar  = MFMA16(ax, bwi[0], zero);
        f32x4 az  = MFMA16(ax, bwi[1], zero);
        f32x4 ani = MFMA16(ax, bwi[2], zero);
        f32x4 anh = zero;
        ar  = MFMA16(ah0, bwh[0][0], ar);
        ar  = MFMA16(ah1, bwh[0][1], ar);
        ar  = MFMA16(ah2, bwh[0][2], ar);
        ar  = MFMA16(ah3, bwh[0][3], ar);
        az  = MFMA16(ah0, bwh[1][0], az);
        az  = MFMA16(ah1, bwh[1][1], az);
        az  = MFMA16(ah2, bwh[1][2], az);
        az  = MFMA16(ah3, bwh[1][3], az);
        anh = MFMA16(ah0, bwh[2][0], anh);
        anh = MFMA16(ah1, bwh[2][1], anh);
        anh = MFMA16(ah2, bwh[2][2], anh);
        anh = MFMA16(ah3, bwh[2][3], anh);

        #pragma unroll
        for (int r = 0; r < 4; ++r) {
            float R  = sigm(ar[r] + br);
            float Z  = sigm(az[r] + bz);
            float Nn = tanh_fast(ani[r] + bni + R * (anh[r] + bnh)); // r gates only h-part
            float hn = Nn + Z * (hreg[r] - Nn);                      // (1-z)n + z h
            hreg[r] = hn;
            hlds[cur ^ 1][rb + r][j] = (_Float16)hn;
        }
        BARRIER();
        cur ^= 1;
    }

    // encoder final hidden -> output tail
    {
        const size_t HOFF = (size_t)Bdim * Sdim * Idim;
        #pragma unroll
        for (int r = 0; r < 4; ++r)
            out[HOFF + (size_t)(row0 + rb + r) * Hdim + j] = hreg[r];
    }

    // ---------------- decoder weights -> registers ----------------
    #pragma unroll
    for (int g = 0; g < 3; ++g) {
        int n = g * Hdim + j;
        bwi[g] = load8(dWih + n * Idim + kb);
        #pragma unroll
        for (int kk = 0; kk < 4; ++kk)
            bwh[g][kk] = load8(dWhh + n * Hdim + kk * 32 + kb);
    }
    br  = dBih[j] + dBhh[j];
    bz  = dBih[Hdim + j] + dBhh[Hdim + j];
    bni = dBih[2 * Hdim + j];
    bnh = dBhh[2 * Hdim + j];

    half8 blin[4];
    float lb = 0.f;
    {
        half8 hz;
        #pragma unroll
        for (int e = 0; e < 8; ++e) hz[e] = (_Float16)0.f;
        blin[0] = hz; blin[1] = hz; blin[2] = hz; blin[3] = hz;
    }
    const int ycol = w * 16 + cc;      // valid (in-range) only for w<2
    if (w < 2) {
        #pragma unroll
        for (int kk = 0; kk < 4; ++kk)
            blin[kk] = load8(linW + ycol * Hdim + kk * 32 + kb);
        lb = linB[ycol];
    }
    if (tid < 128) {                   // decoder seed: x[:,0,:] (h_enc already in hlds[0])
        float4 v = *(const float4*)(x + ((size_t)(row0 + srow) * Sdim + 0) * Idim + sc4);
        half4v hv;
        hv[0] = (_Float16)v.x; hv[1] = (_Float16)v.y; hv[2] = (_Float16)v.z; hv[3] = (_Float16)v.w;
        *(half4v*)&xlds[0][srow][sc4] = hv;
    }
    __syncthreads();

    // ---------------- decoder scan (autoregressive) ----------------
    cur = 0;
    for (int t = 0; t < Sdim; ++t) {
        half8 ax  = *(const half8*)&xlds[cur][cc][kb];
        half8 ah0 = *(const half8*)&hlds[cur][cc][kb];
        half8 ah1 = *(const half8*)&hlds[cur][cc][32 + kb];
        half8 ah2 = *(const half8*)&hlds[cur][cc][64 + kb];
        half8 ah3 = *(const half8*)&hlds[cur][cc][96 + kb];

        f32x4 ar  = MFMA16(ax, bwi[0], zero);
        f32x4 az  = MFMA16(ax, bwi[1], zero);
        f32x4 ani = MFMA16(ax, bwi[2], zero);
        f32x4 anh = zero;
        ar  = MFMA16(ah0, bwh[0][0], ar);
        ar  = MFMA16(ah1, bwh[0][1], ar);
        ar  = MFMA16(ah2, bwh[0][2], ar);
        ar  = MFMA16(ah3, bwh[0][3], ar);
        az  = MFMA16(ah0, bwh[1][0], az);
        az  = MFMA16(ah1, bwh[1][1], az);
        az  = MFMA16(ah2, bwh[1][2], az);
        az  = MFMA16(ah3, bwh[1][3], az);
        anh = MFMA16(ah0, bwh[2][0], anh);
        anh = MFMA16(ah1, bwh[2][1], anh);
        anh = MFMA16(ah2, bwh[2][2], anh);
        anh = MFMA16(ah3, bwh[2][3], anh);

        #pragma unroll
        for (int r = 0; r < 4; ++r) {
            float R  = sigm(ar[r] + br);
            float Z  = sigm(az[r] + bz);
            float Nn = tanh_fast(ani[r] + bni + R * (anh[r] + bnh));
            float hn = Nn + Z * (hreg[r] - Nn);
            hreg[r] = hn;
            hlds[cur ^ 1][rb + r][j] = (_Float16)hn;
        }
        BARRIER();         // h_{t+1} f16 visible for y-GEMM

        if (w < 2) {       // y = h_new @ linW^T + lb ; feed back as next x
            half8 p0 = *(const half8*)&hlds[cur ^ 1][cc][kb];
            half8 p1 = *(const half8*)&hlds[cur ^ 1][cc][32 + kb];
            half8 p2 = *(const half8*)&hlds[cur ^ 1][cc][64 + kb];
            half8 p3 = *(const half8*)&hlds[cur ^ 1][cc][96 + kb];
            f32x4 ay = MFMA16(p0, blin[0], zero);
            ay = MFMA16(p1, blin[1], ay);
            ay = MFMA16(p2, blin[2], ay);
            ay = MFMA16(p3, blin[3], ay);
            #pragma unroll
            for (int r = 0; r < 4; ++r) {
                float yv = ay[r] + lb;
                out[((size_t)(row0 + rb + r) * Sdim + (size_t)t) * Idim + ycol] = yv;
                xlds[cur ^ 1][rb + r][ycol] = (_Float16)yv;
            }
        }
        BARRIER();         // next step's x ready
        cur ^= 1;
    }
}

extern "C" void kernel_launch(void* const* d_in, const int* in_sizes, int n_in,
                              void* d_out, int out_size, void* d_ws, size_t ws_size,
                              hipStream_t stream) {
    (void)in_sizes; (void)n_in; (void)d_ws; (void)ws_size; (void)out_size;
    const float* x    = (const float*)d_in[0];
    const float* h0   = (const float*)d_in[1];
    const float* eWih = (const float*)d_in[2];
    const float* eWhh = (const float*)d_in[3];
    const float* eBih = (const float*)d_in[4];
    const float* eBhh = (const float*)d_in[5];
    const float* dWih = (const float*)d_in[6];
    const float* dWhh = (const float*)d_in[7];
    const float* dBih = (const float*)d_in[8];
    const float* dBhh = (const float*)d_in[9];
    const float* linW = (const float*)d_in[10];
    const float* linB = (const float*)d_in[11];
    rnn_ae<<<dim3(Bdim / ROWS), dim3(THREADS), 0, stream>>>(
        x, h0, eWih, eWhh, eBih, eBhh, dWih, dWhh, dBih, dBhh, linW, linB,
        (float*)d_out);
}